// Round 8
// baseline (396.174 us; speedup 1.0000x reference)
//
#include <hip/hip_runtime.h>

// ---------------- common helpers ----------------
typedef __attribute__((ext_vector_type(8))) short short8;
typedef __attribute__((ext_vector_type(4))) float f32x4;

__device__ __forceinline__ unsigned short f2b(float f) {
    union { float f; unsigned u; } uf; uf.f = f;
    unsigned r = uf.u + 0x7fffu + ((uf.u >> 16) & 1u);   // RNE, finite inputs
    return (unsigned short)(r >> 16);
}
__device__ __forceinline__ float b2f(unsigned short b) {
    union { unsigned u; float f; } uf; uf.u = ((unsigned)b) << 16;
    return uf.f;
}
__device__ __forceinline__ void gload_lds16(const void* g, void* l) {
    __builtin_amdgcn_global_load_lds(
        (const __attribute__((address_space(1))) void*)g,
        (__attribute__((address_space(3))) void*)l,
        16, 0, 0);
}

#define B_SZ 4096
#define F_ST 20
#define F_DY 10
#define MLEN 50
#define E_SZ 16
#define F_ALL 30
#define NPAIR 435
#define DIN 6960
#define KP 7168            /* DIN zero-padded; 8 k-slices of 896 (28 BK=32 steps) */
#define KB1 112            /* w1t kg-blocks: 112 * 8 kg = 896 kg = KP/8 */
#define H_SZ 512
#define BN_EPS 1e-5f

// ============ k_gather: static emb + dynamic masked-mean + lr terms =========
// grid: [0,640) stemb | [640,5760) dyemb | [5760,6272) lr.  512 threads.
__global__ __launch_bounds__(512) void k_gather(
    const int* __restrict__ st_ids, const int* __restrict__ dy_ids,
    const int* __restrict__ dy_len, const float* __restrict__ st_emb,
    const float* __restrict__ dy_emb, const float* __restrict__ st_lr,
    const float* __restrict__ dy_lr, const float* __restrict__ bias,
    float* __restrict__ all_emb, float* __restrict__ lr_score)
{
    int bid = blockIdx.x, t = threadIdx.x;
    if (bid < 640) {                       // ---- static gather, float4/thread
        int idx = bid * 512 + t;           // (b*F_ST+f)*4 + e4
        int e4 = idx & 3, bf = idx >> 2;
        int b = bf / F_ST, f = bf % F_ST;
        int id = st_ids[bf];
        f32x4 v = *(const f32x4*)(st_emb + (long)id * E_SZ + e4 * 4);
        *(f32x4*)(all_emb + ((long)b * F_ALL + f) * E_SZ + e4 * 4) = v;
    } else if (bid < 5760) {               // ---- dynamic mean, 1 wave/(b,f)
        int gw = (bid - 640) * 8 + (t >> 6);
        int l = t & 63;
        int b = gw / F_DY, f = gw - b * F_DY;
        int len = dy_len[b * F_DY + f]; if (len < 1) len = 1;  // wave-uniform
        const int* ids = dy_ids + ((long)b * F_DY + f) * MLEN;
        int idv = (l < MLEN) ? ids[l] : 0;          // coalesced, one load/lane
        int e = l & 15, mq = l >> 4;
        float acc = 0.f;
#pragma unroll
        for (int j = 0; j < 13; ++j) {              // fixed trip: shfl always
            int m = mq + (j << 2);                  // executes with all lanes
            int id = __shfl(idv, m, 64);            // active (m <= 51 < 64)
            float v = (m < len) ? dy_emb[(long)id * E_SZ + e] : 0.f;
            acc += v;
        }
        acc += __shfl_xor(acc, 16, 64);
        acc += __shfl_xor(acc, 32, 64);
        if (l < 16)
            all_emb[((long)b * F_ALL + F_ST + f) * E_SZ + e] = acc / (float)len;
    } else {                               // ---- lr terms, 1 wave/row
        int w = t >> 6, l = t & 63;
        int b = (bid - 5760) * 8 + w;
        float acc = 0.f;
        if (l < F_ST) acc += st_lr[st_ids[b * F_ST + l]];
#pragma unroll
        for (int i = 0; i < 8; ++i) {
            int idx = i * 64 + l;
            if (idx < F_DY * MLEN) {
                int f = idx / MLEN, m = idx - f * MLEN;
                int len = dy_len[b * F_DY + f]; if (len < 1) len = 1;
                if (m < len)
                    acc += dy_lr[dy_ids[((long)b * F_DY + f) * MLEN + m]];
            }
        }
        for (int s = 32; s; s >>= 1) acc += __shfl_down(acc, s, 64);
        if (l == 0) lr_score[b] = bias[0] + acc;
    }
}

// ---------- k_x: pairwise products -> x (bf16, K-padded) + BN1 stats --------
__global__ __launch_bounds__(256) void k_x(
    const float* __restrict__ all_emb, unsigned short* __restrict__ x16,
    float* __restrict__ s1, float* __restrict__ s1q)
{
    __shared__ float es[16 * 480];
    __shared__ int pip[NPAIR], pjp[NPAIR];
    int t = threadIdx.x, b0 = blockIdx.x * 16;
    for (int p = t; p < NPAIR; p += 256) {
        int i = 0, rem = p;
        while (rem >= (F_ALL - 1) - i) { rem -= (F_ALL - 1) - i; ++i; }
        pip[p] = i; pjp[p] = i + 1 + rem;
    }
    for (int idx = t; idx < 16 * 480; idx += 256)
        es[idx] = all_emb[(long)b0 * 480 + idx];
    __syncthreads();

    int ci[28], cj[28];
#pragma unroll
    for (int k = 0; k < 28; ++k) {
        int d = t + (k << 8);
        if (d < DIN) {
            int p = d >> 4, e = d & 15;
            ci[k] = pip[p] * E_SZ + e;
            cj[k] = pjp[p] * E_SZ + e;
        } else { ci[k] = -1; cj[k] = 0; }
    }
    float sum[28], sq[28];
#pragma unroll
    for (int k = 0; k < 28; ++k) { sum[k] = 0.f; sq[k] = 0.f; }

    for (int r = 0; r < 16; ++r) {
        const float* row = &es[r * 480];
        long ob = (long)(b0 + r) * KP;
#pragma unroll
        for (int k = 0; k < 28; ++k) {
            int d = t + (k << 8);
            if (ci[k] >= 0) {
                float v = row[ci[k]] * row[cj[k]];
                unsigned short h = f2b(v);
                x16[ob + d] = h;
                float vb = b2f(h);
                sum[k] += vb; sq[k] += vb * vb;
            } else {
                x16[ob + d] = 0;           // K padding
            }
        }
    }
#pragma unroll
    for (int k = 0; k < 28; ++k) {
        int d = t + (k << 8);
        if (ci[k] >= 0) { atomicAdd(&s1[d], sum[k]); atomicAdd(&s1q[d], sq[k]); }
    }
}

// ============ k_prep: BN1 fold (blocks 0..27) + W3 row-sums (28..59) ========
__global__ __launch_bounds__(256) void k_prep(
    const float* __restrict__ s, const float* __restrict__ sqs,
    const float* __restrict__ g, const float* __restrict__ bb,
    float* __restrict__ a, float* __restrict__ c,
    const float* __restrict__ W3, float* __restrict__ w3s)
{
    int t = threadIdx.x;
    if (blockIdx.x < 28) {
        int d = blockIdx.x * 256 + t;
        if (d < DIN) {
            float m = s[d] * (1.f / 4096.f);
            float var = sqs[d] * (1.f / 4096.f) - m * m;
            float av = g[d] * rsqrtf(var + BN_EPS);
            a[d] = av; c[d] = bb[d] - m * av;
        }
    } else {
        int row = (blockIdx.x - 28) * 16 + (t >> 4), sub = t & 15;
        float acc = 0.f;
        for (int i = 0; i < 32; ++i) acc += W3[(long)row * H_SZ + sub + i * 16];
#pragma unroll
        for (int sh = 8; sh; sh >>= 1) acc += __shfl_xor(acc, sh, 16);
        if (sub == 0) w3s[row] = acc;
    }
}

// ============ k_w1t: w1t[n][k] = a1[k]*W1[k][n] bf16 + conp partials ========
// grid (2, KB1); thread owns col n, 8 kg chunks; NON-atomic partial per block.
__global__ __launch_bounds__(256) void k_w1t(
    const float* __restrict__ W1, const float* __restrict__ a1,
    const float* __restrict__ c1, unsigned short* __restrict__ w1t,
    float* __restrict__ conp)
{
    int t = threadIdx.x;
    int n = blockIdx.x * 256 + t;
    int kb = blockIdx.y;
    float cacc = 0.f;
#pragma unroll
    for (int i = 0; i < 8; ++i) {
        int kg = kb * 8 + i;
        short8 o;
#pragma unroll
        for (int j = 0; j < 8; ++j) {
            int k = kg * 8 + j;
            if (k < DIN) {
                float w = W1[(long)k * H_SZ + n];
                o[j] = (short)f2b(a1[k] * w);
                cacc += c1[k] * w;
            } else o[j] = 0;
        }
        *(short8*)(w1t + (long)n * KP + kg * 8) = o;
    }
    conp[kb * H_SZ + n] = cacc;            // non-atomic partial
}

// ======== k_gemm1: 128x128-tile split-K bf16 MFMA, swizzled LDS =============
// grid (4 col, 32 m, 8 z) = 1024 blocks (4/CU); 256 thr = 4 waves (2x2 of
// 64x64 wave tiles); BK=32, 28 steps; LDS 16 KB. fp32 atomicAdd to accbuf.
// Bank swizzle: chunk c of row r stored at slot (c + (r>>1)) & 3 -> 2-way.
__global__ __launch_bounds__(256, 4) void k_gemm1(
    const unsigned short* __restrict__ A, const unsigned short* __restrict__ Bt,
    float* __restrict__ accbuf)
{
    __shared__ __align__(16) short As[128 * 32];   // 8 KB
    __shared__ __align__(16) short Bs[128 * 32];   // 8 KB
    const int t = threadIdx.x;
    const int w = t >> 6, l = t & 63;
    const int wm = w >> 1, wn = w & 1;
    const int lm = l & 15, lq = l >> 4;
    const int col0 = blockIdx.x * 128;
    const int row0 = blockIdx.y * 128;
    const int k0 = blockIdx.z * (KP / 8);          // 896-wide K slice

    // staging: instr a in {0,1} covers rows a*64 + w*16 + (l>>2)
    const int srow = w * 16 + (l >> 2);            // 0..63
    const int sc0 = ((l & 3) - (l >> 3)) & 3;      // swizzled source chunk
    const unsigned short* gA0 = A + (long)(row0 + srow) * KP + k0 + sc0 * 8;
    const unsigned short* gA1 = A + (long)(row0 + 64 + srow) * KP + k0 + sc0 * 8;
    const unsigned short* gB0 = Bt + (long)(col0 + srow) * KP + k0 + sc0 * 8;
    const unsigned short* gB1 = Bt + (long)(col0 + 64 + srow) * KP + k0 + sc0 * 8;
    short* AsW0 = As + w * 512;                    // + lane*16B appended by HW
    short* AsW1 = As + 2048 + w * 512;
    short* BsW0 = Bs + w * 512;
    short* BsW1 = Bs + 2048 + w * 512;

    f32x4 acc[4][4];
#pragma unroll
    for (int mi = 0; mi < 4; ++mi)
#pragma unroll
        for (int ni = 0; ni < 4; ++ni) acc[mi][ni] = (f32x4){0.f,0.f,0.f,0.f};

    for (int kt = 0; kt < 28; ++kt) {
        gload_lds16(gA0, AsW0);
        gload_lds16(gA1, AsW1);
        gload_lds16(gB0, BsW0);
        gload_lds16(gB1, BsW1);
        __syncthreads();
        short8 af[4];
#pragma unroll
        for (int mi = 0; mi < 4; ++mi) {
            int m = wm * 64 + mi * 16 + lm;
            int sl = (lq + (m >> 1)) & 3;
            af[mi] = *(const short8*)(As + m * 32 + sl * 8);
        }
#pragma unroll
        for (int ni = 0; ni < 4; ++ni) {
            int rb = wn * 64 + ni * 16 + lm;
            int sl = (lq + (rb >> 1)) & 3;
            short8 bf = *(const short8*)(Bs + rb * 32 + sl * 8);
#pragma unroll
            for (int mi = 0; mi < 4; ++mi)
                acc[mi][ni] = __builtin_amdgcn_mfma_f32_16x16x32_bf16(
                    af[mi], bf, acc[mi][ni], 0, 0, 0);
        }
        __syncthreads();
        gA0 += 32; gA1 += 32; gB0 += 32; gB1 += 32;
    }

    // C/D layout: col = lane&15 (n), row = (lane>>4)*4 + reg (m)
#pragma unroll
    for (int ni = 0; ni < 4; ++ni) {
        int col = col0 + wn * 64 + ni * 16 + lm;
#pragma unroll
        for (int mi = 0; mi < 4; ++mi) {
            int rbase = row0 + wm * 64 + mi * 16 + lq * 4;
#pragma unroll
            for (int r = 0; r < 4; ++r)
                atomicAdd(&accbuf[(long)(rbase + r) * H_SZ + col], acc[mi][ni][r]);
        }
    }
}

// ====== k_ep: conp-reduce + accbuf -> relu(.+con1+b1) bf16 r1 + BN2 stats ===
__global__ __launch_bounds__(256) void k_ep(
    const float* __restrict__ accbuf, const float* __restrict__ conp,
    const float* __restrict__ b1, unsigned short* __restrict__ r1,
    float* __restrict__ s2, float* __restrict__ s2q)
{
    __shared__ float con[H_SZ];
    int t = threadIdx.x, r0 = blockIdx.x * 32;
    float c0 = b1[t], c1v = b1[t + 256];
    for (int p = 0; p < KB1; ++p) {
        c0  += conp[p * H_SZ + t];
        c1v += conp[p * H_SZ + t + 256];
    }
    con[t] = c0; con[t + 256] = c1v;
    __syncthreads();
    float a0 = 0.f, q0 = 0.f, a1v = 0.f, q1 = 0.f;
    for (int r = 0; r < 32; ++r) {
        long base = (long)(r0 + r) * H_SZ;
        float v0 = accbuf[base + t] + con[t];
        float v1 = accbuf[base + t + 256] + con[t + 256];
        v0 = v0 > 0.f ? v0 : 0.f;
        v1 = v1 > 0.f ? v1 : 0.f;
        unsigned short h0 = f2b(v0), h1 = f2b(v1);
        r1[base + t] = h0; r1[base + t + 256] = h1;
        float b0 = b2f(h0), b1f = b2f(h1);
        a0 += b0; q0 += b0 * b0; a1v += b1f; q1 += b1f * b1f;
    }
    atomicAdd(&s2[t], a0);        atomicAdd(&s2q[t], q0);
    atomicAdd(&s2[t + 256], a1v); atomicAdd(&s2q[t + 256], q1);
}

// ============ k_w2t: inline BN2 fold + W2^T bf16 cast + con2 ================
__global__ __launch_bounds__(256) void k_w2t(
    const float* __restrict__ W2, const float* __restrict__ s2,
    const float* __restrict__ s2q, const float* __restrict__ g2,
    const float* __restrict__ bb2, unsigned short* __restrict__ w2t,
    float* __restrict__ con)
{
    int gi = blockIdx.x * 256 + threadIdx.x;   // 64 kg * 512 n
    int kg = gi >> 9, n = gi & 511;
    short8 out; float cacc = 0.f;
#pragma unroll
    for (int i = 0; i < 8; ++i) {
        int k = kg * 8 + i;
        float m = s2[k] * (1.f / 4096.f);
        float var = s2q[k] * (1.f / 4096.f) - m * m;
        float av = g2[k] * rsqrtf(var + BN_EPS);
        float cv = bb2[k] - m * av;
        float w = W2[(long)k * H_SZ + n];
        out[i] = (short)f2b(av * w);
        cacc += cv * w;
    }
    *(short8*)(w2t + (long)n * H_SZ + kg * 8) = out;
    atomicAdd(&con[n], cacc);
}

// ============ k_gemm2: full-K bf16 MFMA + fused relu + col stats ============
__global__ __launch_bounds__(512) void k_gemm2(
    const unsigned short* __restrict__ A, const unsigned short* __restrict__ Bt,
    const float* __restrict__ cvec, const float* __restrict__ bvec,
    unsigned short* __restrict__ Out, float* __restrict__ ss,
    float* __restrict__ sq)
{
    const int Kp = H_SZ;
    __shared__ __align__(16) short As[128 * 32];
    __shared__ __align__(16) short Bs[64 * 32];
    const int t = threadIdx.x;
    const int w = t >> 6, l = t & 63;
    const int wm = w >> 1, wn = w & 1;
    const int lm = l & 15, lq = l >> 4;
    const int row0 = blockIdx.y * 128;
    const int col0 = blockIdx.x * 64;

    const unsigned short* gA = A + (long)(row0 + (t >> 2)) * Kp + ((t & 3) * 8);
    const unsigned short* gB = Bt + (long)(col0 + ((t >> 2) & 63)) * Kp + ((t & 3) * 8);
    short* AsW = As + w * 512;
    short* BsW = Bs + w * 512;

    const short* aBase0 = As + (wm * 32 + lm) * 32 + lq * 8;
    const short* aBase1 = aBase0 + 16 * 32;
    const short* bBase0 = Bs + (wn * 32 + lm) * 32 + lq * 8;
    const short* bBase1 = bBase0 + 16 * 32;

    f32x4 acc00 = {0.f,0.f,0.f,0.f}, acc01 = acc00, acc10 = acc00, acc11 = acc00;

    for (int kt = 0; kt < Kp / 32; ++kt) {
        gload_lds16(gA, AsW);
        if (t < 256) gload_lds16(gB, BsW);
        __syncthreads();
        short8 af0 = *(const short8*)aBase0;
        short8 af1 = *(const short8*)aBase1;
        short8 bf0 = *(const short8*)bBase0;
        short8 bf1 = *(const short8*)bBase1;
        acc00 = __builtin_amdgcn_mfma_f32_16x16x32_bf16(af0, bf0, acc00, 0, 0, 0);
        acc01 = __builtin_amdgcn_mfma_f32_16x16x32_bf16(af0, bf1, acc01, 0, 0, 0);
        acc10 = __builtin_amdgcn_mfma_f32_16x16x32_bf16(af1, bf0, acc10, 0, 0, 0);
        acc11 = __builtin_amdgcn_mfma_f32_16x16x32_bf16(af1, bf1, acc11, 0, 0, 0);
        __syncthreads();
        gA += 32; gB += 32;
    }

    f32x4 accs[2][2] = {{acc00, acc01}, {acc10, acc11}};
#pragma unroll
    for (int ni = 0; ni < 2; ++ni) {
        int col = col0 + wn * 32 + ni * 16 + lm;
        float cb = cvec[col] + bvec[col];
        float psum = 0.f, psq = 0.f;
#pragma unroll
        for (int mi = 0; mi < 2; ++mi) {
            int rbase = row0 + wm * 32 + mi * 16 + lq * 4;
#pragma unroll
            for (int r = 0; r < 4; ++r) {
                float v = accs[mi][ni][r] + cb;
                v = v > 0.f ? v : 0.f;
                unsigned short h = f2b(v);
                Out[(long)(rbase + r) * H_SZ + col] = h;
                float vb = b2f(h);
                psum += vb; psq += vb * vb;
            }
        }
        psum += __shfl_xor(psum, 16, 64); psum += __shfl_xor(psum, 32, 64);
        psq  += __shfl_xor(psq , 16, 64); psq  += __shfl_xor(psq , 32, 64);
        if (lq == 0) { atomicAdd(&ss[col], psum); atomicAdd(&sq[col], psq); }
    }
}

// ============ k_final: inline BN3 fold + GEMV + lr ==========================
__global__ __launch_bounds__(256) void k_final(
    const unsigned short* __restrict__ r2, const float* __restrict__ s3,
    const float* __restrict__ s3q, const float* __restrict__ g3,
    const float* __restrict__ bb3, const float* __restrict__ w3s,
    const float* __restrict__ b3, const float* __restrict__ lr_score,
    float* __restrict__ out)
{
    int t = threadIdx.x, w = t >> 6, l = t & 63;
    int b = blockIdx.x * 4 + w;
    float acc = 0.f;
#pragma unroll
    for (int i = 0; i < 8; ++i) {
        int e = i * 64 + l;
        float m = s3[e] * (1.f / 4096.f);
        float var = s3q[e] * (1.f / 4096.f) - m * m;
        float a3 = g3[e] * rsqrtf(var + BN_EPS);
        float c3 = bb3[e] - m * a3;
        float v = a3 * b2f(r2[(long)b * H_SZ + e]) + c3;
        acc += v * w3s[e] + b3[e];
    }
    for (int s = 32; s; s >>= 1) acc += __shfl_down(acc, s, 64);
    if (l == 0) out[b] = lr_score[b] + acc;
}

// ---------------- launcher ----------------
extern "C" void kernel_launch(void* const* d_in, const int* in_sizes, int n_in,
                              void* d_out, int out_size, void* d_ws, size_t ws_size,
                              hipStream_t stream) {
    const int*   st_ids = (const int*)d_in[0];
    const int*   dy_ids = (const int*)d_in[1];
    const int*   dy_len = (const int*)d_in[2];
    const float* st_emb = (const float*)d_in[3];
    const float* dy_emb = (const float*)d_in[4];
    const float* st_lr  = (const float*)d_in[5];
    const float* dy_lr  = (const float*)d_in[6];
    const float* bias   = (const float*)d_in[7];
    const float* bn1_g  = (const float*)d_in[8];
    const float* bn1_b  = (const float*)d_in[9];
    const float* W1     = (const float*)d_in[10];
    const float* b1     = (const float*)d_in[11];
    const float* bn2_g  = (const float*)d_in[12];
    const float* bn2_b  = (const float*)d_in[13];
    const float* W2     = (const float*)d_in[14];
    const float* b2     = (const float*)d_in[15];
    const float* bn3_g  = (const float*)d_in[16];
    const float* bn3_b  = (const float*)d_in[17];
    const float* W3     = (const float*)d_in[18];
    const float* b3     = (const float*)d_in[19];
    // d_in[20..23] feed only the dead final layer — skipped.

    char* ws = (char*)d_ws;
    size_t off = 0;
    auto alloc = [&](size_t bytes) -> char* {
        char* p = ws + off;
        off = (off + bytes + 255) & ~(size_t)255;
        return p;
    };
    // Union region R (8.39 MB), time-multiplexed:
    //   phase 1: all_emb (7.87 MB) | phase 2: accbuf (8.39 MB) | phase 3: r2
    char* R = alloc((size_t)B_SZ * H_SZ * 4);
    float*          all_emb = (float*)R;
    float*          accbuf  = (float*)R;
    unsigned short* r2      = (unsigned short*)R;

    unsigned short* x16     = (unsigned short*)alloc((size_t)B_SZ * KP * 2);
    unsigned short* w1t     = (unsigned short*)alloc((size_t)H_SZ * KP * 2);
    unsigned short* r1      = (unsigned short*)alloc((size_t)B_SZ * H_SZ * 2);
    unsigned short* w2t     = (unsigned short*)alloc((size_t)H_SZ * H_SZ * 2);
    float*          lr_sc   = (float*)alloc(B_SZ * 4);
    float*          conp    = (float*)alloc((size_t)KB1 * H_SZ * 4);
    float* a1  = (float*)alloc(KP * 4);
    float* c1  = (float*)alloc(KP * 4);
    float* w3s = (float*)alloc(H_SZ * 4);
    char* zstart = ws + off;                       // ---- zeroed stats ----
    float* s1   = (float*)alloc(KP * 4);
    float* s1q  = (float*)alloc(KP * 4);
    float* s2   = (float*)alloc(H_SZ * 4);
    float* s2q  = (float*)alloc(H_SZ * 4);
    float* con2 = (float*)alloc(H_SZ * 4);
    float* s3   = (float*)alloc(H_SZ * 4);
    float* s3q  = (float*)alloc(H_SZ * 4);
    size_t zbytes = (size_t)((ws + off) - zstart);
    // total ws use ≈ 79.5 MB (< 81.2 MB proven safe)

    hipMemsetAsync(zstart, 0, zbytes, stream);
    k_gather<<<6272, 512, 0, stream>>>(st_ids, dy_ids, dy_len, st_emb, dy_emb,
                                       st_lr, dy_lr, bias, all_emb, lr_sc);
    k_x<<<B_SZ / 16, 256, 0, stream>>>(all_emb, x16, s1, s1q);
    // all_emb dead; repurpose R as zeroed fp32 accumulator
    hipMemsetAsync(R, 0, (size_t)B_SZ * H_SZ * 4, stream);
    k_prep<<<60, 256, 0, stream>>>(s1, s1q, bn1_g, bn1_b, a1, c1, W3, w3s);
    k_w1t<<<dim3(2, KB1), 256, 0, stream>>>(W1, a1, c1, w1t, conp);
    k_gemm1<<<dim3(4, 32, 8), 256, 0, stream>>>(x16, w1t, accbuf);
    k_ep<<<128, 256, 0, stream>>>(accbuf, conp, b1, r1, s2, s2q);
    k_w2t<<<128, 256, 0, stream>>>(W2, s2, s2q, bn2_g, bn2_b, w2t, con2);
    // accbuf dead; repurpose R as r2
    k_gemm2<<<dim3(8, 32), 512, 0, stream>>>(r1, w2t, con2, b2, r2, s3, s3q);
    k_final<<<B_SZ / 4, 256, 0, stream>>>(r2, s3, s3q, bn3_g, bn3_b, w3s, b3,
                                          lr_sc, (float*)d_out);
}